// Round 3
// baseline (437.116 us; speedup 1.0000x reference)
//
#include <hip/hip_runtime.h>
#include <math.h>

#define BATCH 8
#define SEQL 4096
#define DMODEL 512
#define SDIM 64
#define MROWS (BATCH * SEQL)  // 32768
#define LN_EPS 1e-5f

typedef __attribute__((ext_vector_type(8))) short bf16x8;
typedef __attribute__((ext_vector_type(4))) float f32x4;

// ---------- helpers ----------
__device__ __forceinline__ float wave_sum(float v) {
#pragma unroll
  for (int off = 32; off > 0; off >>= 1) v += __shfl_xor(v, off, 64);
  return v;
}

__device__ __forceinline__ unsigned short f2bf(float f) {  // RNE float->bf16
  unsigned int u = __float_as_uint(f);
  u += 0x7fffu + ((u >> 16) & 1u);
  return (unsigned short)(u >> 16);
}

// fast erf-based gelu (Abramowitz-Stegun 7.1.26, |erf err| <= 1.5e-7)
__device__ __forceinline__ float gelu_fast(float v) {
  float s = v * 0.70710678118654752f;
  float ax = fabsf(s);
  float t = 1.0f / (1.0f + 0.3275911f * ax);
  float p = ((((1.061405429f * t - 1.453152027f) * t + 1.421413741f) * t - 0.284496736f) * t +
             0.254829592f) *
            t;
  float er = 1.0f - p * __expf(-ax * ax);
  er = copysignf(er, s);
  return 0.5f * v * (1.0f + er);
}

__device__ __forceinline__ void gl2lds16(const void* g, void* l) {
  // async global->LDS, 16B/lane; LDS dest = wave-uniform base + lane*16
  __builtin_amdgcn_global_load_lds((const __attribute__((address_space(1))) void*)g,
                                   (__attribute__((address_space(3))) void*)l, 16, 0, 0);
}

// ---------- K1: LN1 stats for x (mu, rstd per row) + bf16 cast of x ----------
__global__ void ln_stats_kernel(const float* __restrict__ x, float* __restrict__ mu,
                                float* __restrict__ rstd, unsigned short* __restrict__ xbf) {
  int row = blockIdx.x * 4 + (threadIdx.x >> 6);
  int lane = threadIdx.x & 63;
  const float4* xp = (const float4*)(x + (size_t)row * DMODEL);
  float4 a = xp[lane * 2];
  float4 b = xp[lane * 2 + 1];
  float s = a.x + a.y + a.z + a.w + b.x + b.y + b.z + b.w;
  float q = a.x * a.x + a.y * a.y + a.z * a.z + a.w * a.w + b.x * b.x + b.y * b.y +
            b.z * b.z + b.w * b.w;
  s = wave_sum(s);
  q = wave_sum(q);
  uint4 pk;
  pk.x = (unsigned)f2bf(a.x) | ((unsigned)f2bf(a.y) << 16);
  pk.y = (unsigned)f2bf(a.z) | ((unsigned)f2bf(a.w) << 16);
  pk.z = (unsigned)f2bf(b.x) | ((unsigned)f2bf(b.y) << 16);
  pk.w = (unsigned)f2bf(b.z) | ((unsigned)f2bf(b.w) << 16);
  ((uint4*)(xbf + (size_t)row * DMODEL))[lane] = pk;
  if (lane == 0) {
    float m = s * (1.0f / DMODEL);
    float var = q * (1.0f / DMODEL) - m * m;
    mu[row] = m;
    rstd[row] = rsqrtf(var + LN_EPS);
  }
}

// ---------- prep: Bgt[s][d]=bf16(gamma[d]*B[d][s]); gB[s]=gamma@B; bB[s]=beta@B ----------
__global__ void prep_b_kernel(const float* __restrict__ Bm, const float* __restrict__ gamma,
                              const float* __restrict__ beta, unsigned short* __restrict__ Bgt,
                              float* __restrict__ gB, float* __restrict__ bB) {
  int s = blockIdx.x;   // 64 blocks
  int l = threadIdx.x;  // 64 threads (1 wave)
  float gs = 0.0f, bs = 0.0f;
  unsigned short tmp[8];
#pragma unroll
  for (int u = 0; u < 8; ++u) {
    int d = l * 8 + u;
    float bv = Bm[(size_t)d * SDIM + s];
    float gv = gamma[d], ev = beta[d];
    gs += gv * bv;
    bs += ev * bv;
    tmp[u] = f2bf(gv * bv);
  }
  *(ushort4*)&Bgt[(size_t)s * DMODEL + l * 8] = make_ushort4(tmp[0], tmp[1], tmp[2], tmp[3]);
  *(ushort4*)&Bgt[(size_t)s * DMODEL + l * 8 + 4] = make_ushort4(tmp[4], tmp[5], tmp[6], tmp[7]);
  gs = wave_sum(gs);
  bs = wave_sum(bs);
  if (l == 0) {
    gB[s] = gs;
    bB[s] = bs;
  }
}

// ---------- transpose+convert: W [K][N] f32 -> Wt [N][K] bf16 ----------
__global__ __launch_bounds__(256) void transpose_bf16_kernel(const float* __restrict__ W,
                                                             unsigned short* __restrict__ Wt,
                                                             int K, int N) {
  __shared__ unsigned short tile[64][65];
  int k0 = blockIdx.y * 64, n0 = blockIdx.x * 64;
  int tx = threadIdx.x & 15, ty = threadIdx.x >> 4;
#pragma unroll
  for (int p = 0; p < 4; ++p) {
    int k = p * 16 + ty;
    float4 v = *(const float4*)&W[(size_t)(k0 + k) * N + n0 + tx * 4];
    tile[tx * 4 + 0][k] = f2bf(v.x);
    tile[tx * 4 + 1][k] = f2bf(v.y);
    tile[tx * 4 + 2][k] = f2bf(v.z);
    tile[tx * 4 + 3][k] = f2bf(v.w);
  }
  __syncthreads();
#pragma unroll
  for (int p = 0; p < 4; ++p) {
    int n = p * 16 + ty;
    ushort4 o;
    o.x = tile[n][tx * 4 + 0];
    o.y = tile[n][tx * 4 + 1];
    o.z = tile[n][tx * 4 + 2];
    o.w = tile[n][tx * 4 + 3];
    *(ushort4*)&Wt[(size_t)(n0 + n) * K + k0 + tx * 4] = o;
  }
}

// ---------- K2: xB = rstd*(xbf@Bgt) - rstd*mu*gB + bB   (MFMA bf16) ----------
// xbf [M][512] bf16; Bgt [64][512] bf16; xB [M][64] f32
__global__ __launch_bounds__(256) void xb_mfma_kernel(
    const unsigned short* __restrict__ xbf, const unsigned short* __restrict__ Bgt,
    const float* __restrict__ mu, const float* __restrict__ rstd, const float* __restrict__ gB,
    const float* __restrict__ bB, float* __restrict__ xB) {
  __shared__ unsigned short As[128 * 32];  // [m][k]
  __shared__ unsigned short Bs[64 * 32];   // [s][k]
  const int t = threadIdx.x;
  const int wave = t >> 6, lane = t & 63;
  const int m0 = blockIdx.x * 128;
  const int wm = wave * 32;
  const int row = t >> 2, seg = t & 3;
  const int fr = lane & 15, fq = lane >> 4;
  f32x4 acc[2][4] = {};
  for (int k0 = 0; k0 < DMODEL; k0 += 32) {
    __syncthreads();
    gl2lds16(xbf + (size_t)(m0 + row) * DMODEL + k0 + seg * 8, As + (size_t)(wave * 16) * 32);
    gl2lds16(xbf + (size_t)(m0 + 64 + row) * DMODEL + k0 + seg * 8,
             As + (size_t)(64 + wave * 16) * 32);
    gl2lds16(Bgt + (size_t)row * DMODEL + k0 + seg * 8, Bs + (size_t)(wave * 16) * 32);
    __syncthreads();
#pragma unroll
    for (int i = 0; i < 2; ++i) {
      bf16x8 a = *(const bf16x8*)&As[(wm + i * 16 + fr) * 32 + fq * 8];
#pragma unroll
      for (int j = 0; j < 4; ++j) {
        bf16x8 b = *(const bf16x8*)&Bs[(j * 16 + fr) * 32 + fq * 8];
        acc[i][j] = __builtin_amdgcn_mfma_f32_16x16x32_bf16(a, b, acc[i][j], 0, 0, 0);
      }
    }
  }
#pragma unroll
  for (int i = 0; i < 2; ++i)
#pragma unroll
    for (int r = 0; r < 4; ++r) {
      const int m = m0 + wm + i * 16 + fq * 4 + r;
      const float rr = rstd[m], negmurr = -mu[m] * rstd[m];
#pragma unroll
      for (int j = 0; j < 4; ++j) {
        const int s = j * 16 + fr;
        xB[(size_t)m * SDIM + s] = rr * acc[i][j][r] + negmurr * gB[s] + bB[s];
      }
    }
}

// ---------- K3a/b/c: exact chunked scan h_t = a*h_{t-1} + x_t over L ----------
__global__ void scan_ends_kernel(const float* __restrict__ xB, const float* __restrict__ logA,
                                 const float* __restrict__ logdt, float* __restrict__ ends) {
  int t = blockIdx.x * 256 + threadIdx.x;
  int s = t & 63;
  int c = (t >> 6) & 63;
  int b = t >> 12;
  float a = expf(-expf(logA[s]) * expf(logdt[0]));
  const float* p = xB + ((size_t)(b * SEQL + c * 64)) * SDIM + s;
  float e = 0.0f;
#pragma unroll
  for (int i = 0; i < 64; ++i) e = a * e + p[(size_t)i * SDIM];
  ends[(b * 64 + c) * 64 + s] = e;
}

__global__ void scan_carry_kernel(const float* __restrict__ ends, const float* __restrict__ logA,
                                  const float* __restrict__ logdt,
                                  float* __restrict__ carries) {
  int t = blockIdx.x * 256 + threadIdx.x;
  int s = t & 63;
  int b = t >> 6;
  float a = expf(-expf(logA[s]) * expf(logdt[0]));
  float a64 = a;
#pragma unroll
  for (int i = 0; i < 6; ++i) a64 *= a64;
  float carry = 0.0f;
  for (int c = 0; c < 64; ++c) {
    carries[(b * 64 + c) * 64 + s] = carry;
    carry = a64 * carry + ends[(b * 64 + c) * 64 + s];
  }
}

__global__ void scan_fix_kernel(const float* __restrict__ logA, const float* __restrict__ logdt,
                                const float* __restrict__ carries, const float* __restrict__ xB,
                                unsigned short* __restrict__ hsb) {
  int t = blockIdx.x * 256 + threadIdx.x;
  int s = t & 63;
  int c = (t >> 6) & 63;
  int b = t >> 12;
  float a = expf(-expf(logA[s]) * expf(logdt[0]));
  float h = carries[(b * 64 + c) * 64 + s];
  const float* p = xB + ((size_t)(b * SEQL + c * 64)) * SDIM + s;
  unsigned short* q = hsb + ((size_t)(b * SEQL + c * 64)) * SDIM + s;
#pragma unroll
  for (int i = 0; i < 64; ++i) {
    h = a * h + p[(size_t)i * SDIM];
    q[(size_t)i * SDIM] = f2bf(h);
  }
}

// ---------- K4: fused y = hsb@Ctb + xn*D + x -> out ; yn = bf16(LN2(y)) ----------
// Block: 64 rows x 512 cols, K=64 fully staged. 4 waves, wave w -> cols w*128..+127.
__global__ __launch_bounds__(256, 2) void y_ln_fused_kernel(
    const unsigned short* __restrict__ hsb, const unsigned short* __restrict__ ctb,
    const float* __restrict__ x, const float* __restrict__ mu1, const float* __restrict__ rstd1,
    const float* __restrict__ gamma, const float* __restrict__ beta,
    const float* __restrict__ Dv, float* __restrict__ out, unsigned short* __restrict__ yn) {
  __shared__ unsigned short As[64 * 64];    // hsb tile  [row][k]  8 KB
  __shared__ unsigned short Bs[512 * 64];   // ctb (all) [d][s]   64 KB
  __shared__ float redS[64 * 4], redQ[64 * 4], meanA[64], rsA[64];
  const int t = threadIdx.x;
  const int w = t >> 6, lane = t & 63;
  const int m0 = blockIdx.x * 64;
  const int fr = lane & 15, fq = lane >> 4;
  // stage A: 2 chunks of 256 lanes (rows t>>3, segs t&7)
  {
    const int arow = t >> 3, aseg = t & 7;
    gl2lds16(hsb + (size_t)(m0 + arow) * SDIM + aseg * 8, As + (size_t)(w * 8) * 64);
    gl2lds16(hsb + (size_t)(m0 + 32 + arow) * SDIM + aseg * 8,
             As + (size_t)(32 + w * 8) * 64);
// stage B: 16 linear chunks of 4 KB
#pragma unroll
    for (int c = 0; c < 16; ++c)
      gl2lds16(ctb + (size_t)c * 2048 + (size_t)t * 8, Bs + (size_t)c * 2048 + (size_t)w * 512);
  }
  __syncthreads();
  f32x4 acc[4][8] = {};
#pragma unroll
  for (int k0 = 0; k0 < 64; k0 += 32) {
    bf16x8 a[4];
#pragma unroll
    for (int i = 0; i < 4; ++i) a[i] = *(const bf16x8*)&As[(i * 16 + fr) * 64 + k0 + fq * 8];
#pragma unroll
    for (int j = 0; j < 8; ++j) {
      bf16x8 b = *(const bf16x8*)&Bs[(w * 128 + j * 16 + fr) * 64 + k0 + fq * 8];
#pragma unroll
      for (int i = 0; i < 4; ++i)
        acc[i][j] = __builtin_amdgcn_mfma_f32_16x16x32_bf16(a[i], b, acc[i][j], 0, 0, 0);
    }
  }
  // pass 1: finalize y = acc + xn*D + x, store out, accumulate row sums
  float sum_[4][4] = {}, sq_[4][4] = {};
  float mm[4][4], rr[4][4];
#pragma unroll
  for (int i = 0; i < 4; ++i)
#pragma unroll
    for (int r = 0; r < 4; ++r) {
      int m = m0 + i * 16 + fq * 4 + r;
      mm[i][r] = mu1[m];
      rr[i][r] = rstd1[m];
    }
#pragma unroll
  for (int j = 0; j < 8; ++j) {
    const int n = w * 128 + j * 16 + fr;
    const float ga = gamma[n], be = beta[n], dd = Dv[n];
#pragma unroll
    for (int i = 0; i < 4; ++i)
#pragma unroll
      for (int r = 0; r < 4; ++r) {
        const int m = m0 + i * 16 + fq * 4 + r;
        const float xv = x[(size_t)m * DMODEL + n];
        float yv = acc[i][j][r] + ((xv - mm[i][r]) * rr[i][r] * ga + be) * dd + xv;
        acc[i][j][r] = yv;
        out[(size_t)m * DMODEL + n] = yv;
        sum_[i][r] += yv;
        sq_[i][r] += yv * yv;
      }
  }
  // reduce over the 16 fr-lanes (same rows, different cols)
#pragma unroll
  for (int i = 0; i < 4; ++i)
#pragma unroll
    for (int r = 0; r < 4; ++r) {
      float s = sum_[i][r], q = sq_[i][r];
#pragma unroll
      for (int off = 1; off < 16; off <<= 1) {
        s += __shfl_xor(s, off, 64);
        q += __shfl_xor(q, off, 64);
      }
      sum_[i][r] = s;
      sq_[i][r] = q;
    }
  if (fr == 0) {
#pragma unroll
    for (int i = 0; i < 4; ++i)
#pragma unroll
      for (int r = 0; r < 4; ++r) {
        const int rl = i * 16 + fq * 4 + r;
        redS[rl * 4 + w] = sum_[i][r];
        redQ[rl * 4 + w] = sq_[i][r];
      }
  }
  __syncthreads();
  if (t < 64) {
    float s = redS[t * 4] + redS[t * 4 + 1] + redS[t * 4 + 2] + redS[t * 4 + 3];
    float q = redQ[t * 4] + redQ[t * 4 + 1] + redQ[t * 4 + 2] + redQ[t * 4 + 3];
    float mean = s * (1.0f / DMODEL);
    float var = q * (1.0f / DMODEL) - mean * mean;
    meanA[t] = mean;
    rsA[t] = rsqrtf(var + LN_EPS);
  }
  __syncthreads();
  // pass 2: yn = bf16((y - mean) * rs * gamma + beta)
#pragma unroll
  for (int j = 0; j < 8; ++j) {
    const int n = w * 128 + j * 16 + fr;
    const float ga = gamma[n], be = beta[n];
#pragma unroll
    for (int i = 0; i < 4; ++i)
#pragma unroll
      for (int r = 0; r < 4; ++r) {
        const int rl = i * 16 + fq * 4 + r;
        const float yv = acc[i][j][r];
        yn[(size_t)(m0 + rl) * DMODEL + n] = f2bf((yv - meanA[rl]) * rsA[rl] * ga + be);
      }
  }
}

// ---------- MFMA MLP GEMM 1: g = bf16(gelu(yn @ W1 + b1)) ----------
__global__ __launch_bounds__(256) void mlp1_mfma_kernel(const unsigned short* __restrict__ yn,
                                                        const unsigned short* __restrict__ w1t,
                                                        const float* __restrict__ b1,
                                                        unsigned short* __restrict__ g) {
  __shared__ unsigned short As[128 * 32];
  __shared__ unsigned short Bs[128 * 32];
  const int t = threadIdx.x;
  const int wave = t >> 6, lane = t & 63;
  const int m0 = blockIdx.y * 128, n0 = blockIdx.x * 128;
  const int wm = (wave >> 1) * 64, wn = (wave & 1) * 64;
  const int row0 = t >> 2, seg0 = t & 3;
  const int row1 = (t + 256) >> 2;
  const unsigned short* gA0 = yn + (size_t)(m0 + row0) * 512 + seg0 * 8;
  const unsigned short* gA1 = yn + (size_t)(m0 + row1) * 512 + seg0 * 8;
  const unsigned short* gB0 = w1t + (size_t)(n0 + row0) * 512 + seg0 * 8;
  const unsigned short* gB1 = w1t + (size_t)(n0 + row1) * 512 + seg0 * 8;
  unsigned short* lA0 = As + (size_t)(wave * 64) * 8;
  unsigned short* lA1 = As + (size_t)(256 + wave * 64) * 8;
  unsigned short* lB0 = Bs + (size_t)(wave * 64) * 8;
  unsigned short* lB1 = Bs + (size_t)(256 + wave * 64) * 8;
  f32x4 acc[4][4] = {};
  const int fr = lane & 15, fq = lane >> 4;
  for (int k0 = 0; k0 < 512; k0 += 32) {
    __syncthreads();
    gl2lds16(gA0 + k0, lA0);
    gl2lds16(gA1 + k0, lA1);
    gl2lds16(gB0 + k0, lB0);
    gl2lds16(gB1 + k0, lB1);
    __syncthreads();
#pragma unroll
    for (int i = 0; i < 4; ++i) {
      bf16x8 a = *(const bf16x8*)&As[(wm + i * 16 + fr) * 32 + fq * 8];
#pragma unroll
      for (int j = 0; j < 4; ++j) {
        bf16x8 b = *(const bf16x8*)&Bs[(wn + j * 16 + fr) * 32 + fq * 8];
        acc[i][j] = __builtin_amdgcn_mfma_f32_16x16x32_bf16(a, b, acc[i][j], 0, 0, 0);
      }
    }
  }
#pragma unroll
  for (int i = 0; i < 4; ++i)
#pragma unroll
    for (int j = 0; j < 4; ++j) {
      const int cg = n0 + wn + j * 16 + fr;
      const float bb = b1[cg];
#pragma unroll
      for (int r = 0; r < 4; ++r) {
        const int rg = m0 + wm + i * 16 + fq * 4 + r;
        g[(size_t)rg * 1024 + cg] = f2bf(gelu_fast(acc[i][j][r] + bb));
      }
    }
}

// ---------- MFMA MLP GEMM 2: out = y + g @ W2 + b2 ----------
__global__ __launch_bounds__(256) void mlp2_mfma_kernel(const unsigned short* __restrict__ g,
                                                        const unsigned short* __restrict__ w2t,
                                                        const float* __restrict__ b2,
                                                        float* __restrict__ out) {
  __shared__ unsigned short As[128 * 32];
  __shared__ unsigned short Bs[128 * 32];
  const int t = threadIdx.x;
  const int wave = t >> 6, lane = t & 63;
  const int m0 = blockIdx.y * 128, n0 = blockIdx.x * 128;
  const int wm = (wave >> 1) * 64, wn = (wave & 1) * 64;
  const int row0 = t >> 2, seg0 = t & 3;
  const int row1 = (t + 256) >> 2;
  const unsigned short* gA0 = g + (size_t)(m0 + row0) * 1024 + seg0 * 8;
  const unsigned short* gA1 = g + (size_t)(m0 + row1) * 1024 + seg0 * 8;
  const unsigned short* gB0 = w2t + (size_t)(n0 + row0) * 1024 + seg0 * 8;
  const unsigned short* gB1 = w2t + (size_t)(n0 + row1) * 1024 + seg0 * 8;
  unsigned short* lA0 = As + (size_t)(wave * 64) * 8;
  unsigned short* lA1 = As + (size_t)(256 + wave * 64) * 8;
  unsigned short* lB0 = Bs + (size_t)(wave * 64) * 8;
  unsigned short* lB1 = Bs + (size_t)(256 + wave * 64) * 8;
  f32x4 acc[4][4] = {};
  const int fr = lane & 15, fq = lane >> 4;
  for (int k0 = 0; k0 < 1024; k0 += 32) {
    __syncthreads();
    gl2lds16(gA0 + k0, lA0);
    gl2lds16(gA1 + k0, lA1);
    gl2lds16(gB0 + k0, lB0);
    gl2lds16(gB1 + k0, lB1);
    __syncthreads();
#pragma unroll
    for (int i = 0; i < 4; ++i) {
      bf16x8 a = *(const bf16x8*)&As[(wm + i * 16 + fr) * 32 + fq * 8];
#pragma unroll
      for (int j = 0; j < 4; ++j) {
        bf16x8 b = *(const bf16x8*)&Bs[(wn + j * 16 + fr) * 32 + fq * 8];
        acc[i][j] = __builtin_amdgcn_mfma_f32_16x16x32_bf16(a, b, acc[i][j], 0, 0, 0);
      }
    }
  }
#pragma unroll
  for (int i = 0; i < 4; ++i)
#pragma unroll
    for (int j = 0; j < 4; ++j) {
      const int cg = n0 + wn + j * 16 + fr;
      const float bb = b2[cg];
#pragma unroll
      for (int r = 0; r < 4; ++r) {
        const int rg = m0 + wm + i * 16 + fq * 4 + r;
        const size_t off = (size_t)rg * 512 + cg;
        out[off] = out[off] + acc[i][j][r] + bb;
      }
    }
}

extern "C" void kernel_launch(void* const* d_in, const int* in_sizes, int n_in, void* d_out,
                              int out_size, void* d_ws, size_t ws_size, hipStream_t stream) {
  const float* x = (const float*)d_in[0];
  const float* logA = (const float*)d_in[1];
  const float* Bm = (const float*)d_in[2];
  const float* Cm = (const float*)d_in[3];
  const float* Dv = (const float*)d_in[4];
  const float* logdt = (const float*)d_in[5];
  const float* gamma = (const float*)d_in[6];
  const float* beta = (const float*)d_in[7];
  const float* W1 = (const float*)d_in[8];
  const float* b1 = (const float*)d_in[9];
  const float* W2 = (const float*)d_in[10];
  const float* b2 = (const float*)d_in[11];
  float* out = (float*)d_out;

  // workspace layout (bytes), total ~110.6 MB. xbf aliases the (later) g region.
  char* ws = (char*)d_ws;
  float* mu1 = (float*)(ws + 0);
  float* rstd1 = (float*)(ws + 131072);
  float* ends = (float*)(ws + 262144);
  float* carries = (float*)(ws + 393216);
  float* gB = (float*)(ws + 524288);
  float* bB = (float*)(ws + 524800);
  unsigned short* Bgt = (unsigned short*)(ws + 525312);   // 64 KB [64][512]
  unsigned short* ctb = (unsigned short*)(ws + 590848);   // 64 KB [512][64]
  unsigned short* w1t = (unsigned short*)(ws + 656384);   // 1 MB  [1024][512]
  unsigned short* w2t = (unsigned short*)(ws + 1704960);  // 1 MB  [512][1024]
  unsigned short* g = (unsigned short*)(ws + 2753536);    // 64 MB [32768][1024]
  unsigned short* xbf = (unsigned short*)(ws + 2753536);  // 32 MB (dead before g written)
  float* xB = (float*)(ws + 69862400);                    // 8 MB [M][64]
  unsigned short* hsb = (unsigned short*)(ws + 78251008); // 4 MB bf16 [M][64]
  unsigned short* yn = (unsigned short*)(ws + 82445312);  // 32 MB bf16

  // weight prep (input-independent, cheap)
  transpose_bf16_kernel<<<dim3(1024 / 64, 512 / 64), 256, 0, stream>>>(W1, w1t, 512, 1024);
  transpose_bf16_kernel<<<dim3(512 / 64, 1024 / 64), 256, 0, stream>>>(W2, w2t, 1024, 512);
  transpose_bf16_kernel<<<dim3(512 / 64, 1), 256, 0, stream>>>(Cm, ctb, 64, 512);
  prep_b_kernel<<<64, 64, 0, stream>>>(Bm, gamma, beta, Bgt, gB, bB);

  ln_stats_kernel<<<MROWS / 4, 256, 0, stream>>>(x, mu1, rstd1, xbf);
  xb_mfma_kernel<<<MROWS / 128, 256, 0, stream>>>(xbf, Bgt, mu1, rstd1, gB, bB, xB);
  scan_ends_kernel<<<128, 256, 0, stream>>>(xB, logA, logdt, ends);
  scan_carry_kernel<<<2, 256, 0, stream>>>(ends, logA, logdt, carries);
  scan_fix_kernel<<<128, 256, 0, stream>>>(logA, logdt, carries, xB, hsb);
  y_ln_fused_kernel<<<MROWS / 64, 256, 0, stream>>>(hsb, ctb, x, mu1, rstd1, gamma, beta, Dv,
                                                    out, yn);
  mlp1_mfma_kernel<<<dim3(1024 / 128, MROWS / 128), 256, 0, stream>>>(yn, w1t, b1, g);
  mlp2_mfma_kernel<<<dim3(512 / 128, MROWS / 128), 256, 0, stream>>>(g, w2t, b2, out);
}

// Round 4
// 343.350 us; speedup vs baseline: 1.2731x; 1.2731x over previous
//
#include <hip/hip_runtime.h>
#include <math.h>

#define BATCH 8
#define SEQL 4096
#define DMODEL 512
#define SDIM 64
#define MROWS (BATCH * SEQL)  // 32768
#define LN_EPS 1e-5f

typedef __attribute__((ext_vector_type(8))) short bf16x8;
typedef __attribute__((ext_vector_type(4))) float f32x4;

// ---------- helpers ----------
__device__ __forceinline__ float wave_sum(float v) {
#pragma unroll
  for (int off = 32; off > 0; off >>= 1) v += __shfl_xor(v, off, 64);
  return v;
}

__device__ __forceinline__ unsigned short f2bf(float f) {  // RNE float->bf16
  unsigned int u = __float_as_uint(f);
  u += 0x7fffu + ((u >> 16) & 1u);
  return (unsigned short)(u >> 16);
}

// fast erf-based gelu (Abramowitz-Stegun 7.1.26, |erf err| <= 1.5e-7)
__device__ __forceinline__ float gelu_fast(float v) {
  float s = v * 0.70710678118654752f;
  float ax = fabsf(s);
  float t = 1.0f / (1.0f + 0.3275911f * ax);
  float p = ((((1.061405429f * t - 1.453152027f) * t + 1.421413741f) * t - 0.284496736f) * t +
             0.254829592f) *
            t;
  float er = 1.0f - p * __expf(-ax * ax);
  er = copysignf(er, s);
  return 0.5f * v * (1.0f + er);
}

__device__ __forceinline__ void gl2lds16(const void* g, void* l) {
  // async global->LDS, 16B/lane; LDS dest = wave-uniform base + lane*16
  __builtin_amdgcn_global_load_lds((const __attribute__((address_space(1))) void*)g,
                                   (__attribute__((address_space(3))) void*)l, 16, 0, 0);
}

// ---------- K1: LN1 stats for x (mu, rstd per row) + bf16 cast of x ----------
__global__ void ln_stats_kernel(const float* __restrict__ x, float* __restrict__ mu,
                                float* __restrict__ rstd, unsigned short* __restrict__ xbf) {
  int row = blockIdx.x * 4 + (threadIdx.x >> 6);
  int lane = threadIdx.x & 63;
  const float4* xp = (const float4*)(x + (size_t)row * DMODEL);
  float4 a = xp[lane * 2];
  float4 b = xp[lane * 2 + 1];
  float s = a.x + a.y + a.z + a.w + b.x + b.y + b.z + b.w;
  float q = a.x * a.x + a.y * a.y + a.z * a.z + a.w * a.w + b.x * b.x + b.y * b.y +
            b.z * b.z + b.w * b.w;
  s = wave_sum(s);
  q = wave_sum(q);
  uint4 pk;
  pk.x = (unsigned)f2bf(a.x) | ((unsigned)f2bf(a.y) << 16);
  pk.y = (unsigned)f2bf(a.z) | ((unsigned)f2bf(a.w) << 16);
  pk.z = (unsigned)f2bf(b.x) | ((unsigned)f2bf(b.y) << 16);
  pk.w = (unsigned)f2bf(b.z) | ((unsigned)f2bf(b.w) << 16);
  ((uint4*)(xbf + (size_t)row * DMODEL))[lane] = pk;
  if (lane == 0) {
    float m = s * (1.0f / DMODEL);
    float var = q * (1.0f / DMODEL) - m * m;
    mu[row] = m;
    rstd[row] = rsqrtf(var + LN_EPS);
  }
}

// ---------- prep: all weight transposes + B-prep in ONE kernel ----------
__device__ __forceinline__ void transpose_body(const float* __restrict__ W,
                                               unsigned short* __restrict__ Wt, int K, int N,
                                               int bx, int by,
                                               unsigned short (*tile)[65]) {
  int k0 = by * 64, n0 = bx * 64;
  int tx = threadIdx.x & 15, ty = threadIdx.x >> 4;
#pragma unroll
  for (int p = 0; p < 4; ++p) {
    int k = p * 16 + ty;
    float4 v = *(const float4*)&W[(size_t)(k0 + k) * N + n0 + tx * 4];
    tile[tx * 4 + 0][k] = f2bf(v.x);
    tile[tx * 4 + 1][k] = f2bf(v.y);
    tile[tx * 4 + 2][k] = f2bf(v.z);
    tile[tx * 4 + 3][k] = f2bf(v.w);
  }
  __syncthreads();
#pragma unroll
  for (int p = 0; p < 4; ++p) {
    int n = p * 16 + ty;
    ushort4 o;
    o.x = tile[n][tx * 4 + 0];
    o.y = tile[n][tx * 4 + 1];
    o.z = tile[n][tx * 4 + 2];
    o.w = tile[n][tx * 4 + 3];
    *(ushort4*)&Wt[(size_t)(n0 + n) * K + k0 + tx * 4] = o;
  }
}

__global__ __launch_bounds__(256) void prep_all_kernel(
    const float* __restrict__ W1, const float* __restrict__ W2, const float* __restrict__ Cm,
    const float* __restrict__ Bm, const float* __restrict__ gamma,
    const float* __restrict__ beta, unsigned short* __restrict__ w1t,
    unsigned short* __restrict__ w2t, unsigned short* __restrict__ ctb,
    unsigned short* __restrict__ Bgt, float* __restrict__ gB, float* __restrict__ bB) {
  __shared__ unsigned short tile[64][65];
  int b = blockIdx.x;
  if (b < 128) {  // W1 [512][1024] -> w1t [1024][512]
    transpose_body(W1, w1t, 512, 1024, b & 15, b >> 4, tile);
  } else if (b < 256) {  // W2 [1024][512] -> w2t [512][1024]
    transpose_body(W2, w2t, 1024, 512, (b - 128) & 7, (b - 128) >> 3, tile);
  } else if (b < 264) {  // Cm [64][512] -> ctb [512][64]
    transpose_body(Cm, ctb, 64, 512, b - 256, 0, tile);
  } else {  // Bgt[s][d]=bf16(gamma[d]*B[d][s]); gB[s]=gamma@B; bB[s]=beta@B
    int s = (b - 264) * 4 + (threadIdx.x >> 6);
    int l = threadIdx.x & 63;
    float gs = 0.0f, bs = 0.0f;
    unsigned short tmp[8];
#pragma unroll
    for (int u = 0; u < 8; ++u) {
      int d = l * 8 + u;
      float bv = Bm[(size_t)d * SDIM + s];
      float gv = gamma[d], ev = beta[d];
      gs += gv * bv;
      bs += ev * bv;
      tmp[u] = f2bf(gv * bv);
    }
    *(ushort4*)&Bgt[(size_t)s * DMODEL + l * 8] = make_ushort4(tmp[0], tmp[1], tmp[2], tmp[3]);
    *(ushort4*)&Bgt[(size_t)s * DMODEL + l * 8 + 4] =
        make_ushort4(tmp[4], tmp[5], tmp[6], tmp[7]);
    gs = wave_sum(gs);
    bs = wave_sum(bs);
    if (l == 0) {
      gB[s] = gs;
      bB[s] = bs;
    }
  }
}

// ---------- K2: xB = rstd*(xbf@Bgt) - rstd*mu*gB + bB   (MFMA bf16) ----------
__global__ __launch_bounds__(256) void xb_mfma_kernel(
    const unsigned short* __restrict__ xbf, const unsigned short* __restrict__ Bgt,
    const float* __restrict__ mu, const float* __restrict__ rstd, const float* __restrict__ gB,
    const float* __restrict__ bB, float* __restrict__ xB) {
  __shared__ unsigned short As[128 * 32];  // [m][k]
  __shared__ unsigned short Bs[64 * 32];   // [s][k]
  const int t = threadIdx.x;
  const int wave = t >> 6, lane = t & 63;
  const int m0 = blockIdx.x * 128;
  const int wm = wave * 32;
  const int row = t >> 2, seg = t & 3;
  const int fr = lane & 15, fq = lane >> 4;
  f32x4 acc[2][4] = {};
  for (int k0 = 0; k0 < DMODEL; k0 += 32) {
    __syncthreads();
    gl2lds16(xbf + (size_t)(m0 + row) * DMODEL + k0 + seg * 8, As + (size_t)(wave * 16) * 32);
    gl2lds16(xbf + (size_t)(m0 + 64 + row) * DMODEL + k0 + seg * 8,
             As + (size_t)(64 + wave * 16) * 32);
    gl2lds16(Bgt + (size_t)row * DMODEL + k0 + seg * 8, Bs + (size_t)(wave * 16) * 32);
    __syncthreads();
#pragma unroll
    for (int i = 0; i < 2; ++i) {
      bf16x8 a = *(const bf16x8*)&As[(wm + i * 16 + fr) * 32 + fq * 8];
#pragma unroll
      for (int j = 0; j < 4; ++j) {
        bf16x8 b = *(const bf16x8*)&Bs[(j * 16 + fr) * 32 + fq * 8];
        acc[i][j] = __builtin_amdgcn_mfma_f32_16x16x32_bf16(a, b, acc[i][j], 0, 0, 0);
      }
    }
  }
#pragma unroll
  for (int i = 0; i < 2; ++i)
#pragma unroll
    for (int r = 0; r < 4; ++r) {
      const int m = m0 + wm + i * 16 + fq * 4 + r;
      const float rr = rstd[m], negmurr = -mu[m] * rstd[m];
#pragma unroll
      for (int j = 0; j < 4; ++j) {
        const int s = j * 16 + fr;
        xB[(size_t)m * SDIM + s] = rr * acc[i][j][r] + negmurr * gB[s] + bB[s];
      }
    }
}

// ---------- K3a/b: exact chunked scan h_t = a*h_{t-1} + x_t over L ----------
__global__ void scan_ends_kernel(const float* __restrict__ xB, const float* __restrict__ logA,
                                 const float* __restrict__ logdt, float* __restrict__ ends) {
  int t = blockIdx.x * 256 + threadIdx.x;
  int s = t & 63;
  int c = (t >> 6) & 63;
  int b = t >> 12;
  float a = expf(-expf(logA[s]) * expf(logdt[0]));
  const float* p = xB + ((size_t)(b * SEQL + c * 64)) * SDIM + s;
  float e = 0.0f;
#pragma unroll
  for (int i = 0; i < 64; ++i) e = a * e + p[(size_t)i * SDIM];
  ends[(b * 64 + c) * 64 + s] = e;
}

// carry inlined: each wave (uniform c) recomputes its chunk-entry state from ends (L2-hot)
__global__ void scan_fix_kernel(const float* __restrict__ logA, const float* __restrict__ logdt,
                                const float* __restrict__ ends, const float* __restrict__ xB,
                                unsigned short* __restrict__ hsb) {
  int t = blockIdx.x * 256 + threadIdx.x;
  int s = t & 63;
  int c = (t >> 6) & 63;
  int b = t >> 12;
  float a = expf(-expf(logA[s]) * expf(logdt[0]));
  float a64 = a;
#pragma unroll
  for (int i = 0; i < 6; ++i) a64 *= a64;  // a^64
  float h = 0.0f;
  for (int cp = 0; cp < c; ++cp) h = a64 * h + ends[(b * 64 + cp) * 64 + s];
  const float* p = xB + ((size_t)(b * SEQL + c * 64)) * SDIM + s;
  unsigned short* q = hsb + ((size_t)(b * SEQL + c * 64)) * SDIM + s;
#pragma unroll
  for (int i = 0; i < 64; ++i) {
    h = a * h + p[(size_t)i * SDIM];
    q[(size_t)i * SDIM] = f2bf(h);
  }
}

// ---------- K4: y = hsb@ctb^T + xn*D + x -> out   (MFMA, 128x128 tile, K=64) ----------
__global__ __launch_bounds__(256) void y_gemm_mfma_kernel(
    const unsigned short* __restrict__ hsb, const unsigned short* __restrict__ ctb,
    const float* __restrict__ x, const float* __restrict__ mu1,
    const float* __restrict__ rstd1, const float* __restrict__ gamma,
    const float* __restrict__ beta, const float* __restrict__ Dv, float* __restrict__ out) {
  __shared__ unsigned short As[2 * 128 * 32];  // [h][row][k32]
  __shared__ unsigned short Bs[2 * 128 * 32];  // [h][n][k32]
  const int t = threadIdx.x;
  const int w = t >> 6, lane = t & 63;
  const int m0 = blockIdx.y * 128, n0 = blockIdx.x * 128;
  const int wm = (w >> 1) * 64, wn = (w & 1) * 64;
  const int fr = lane & 15, fq = lane >> 4;
  const int srow = t >> 2, sseg = t & 3;  // 256 lanes: 64 rows x 4x8 bf16
#pragma unroll
  for (int h = 0; h < 2; ++h)
#pragma unroll
    for (int c = 0; c < 2; ++c) {
      gl2lds16(hsb + (size_t)(m0 + c * 64 + srow) * SDIM + h * 32 + sseg * 8,
               As + ((size_t)h * 128 + c * 64 + w * 16) * 32);
      gl2lds16(ctb + (size_t)(n0 + c * 64 + srow) * SDIM + h * 32 + sseg * 8,
               Bs + ((size_t)h * 128 + c * 64 + w * 16) * 32);
    }
  __syncthreads();
  f32x4 acc[4][4] = {};
#pragma unroll
  for (int h = 0; h < 2; ++h) {
    bf16x8 a[4], b[4];
#pragma unroll
    for (int i = 0; i < 4; ++i)
      a[i] = *(const bf16x8*)&As[((size_t)h * 128 + wm + i * 16 + fr) * 32 + fq * 8];
#pragma unroll
    for (int j = 0; j < 4; ++j)
      b[j] = *(const bf16x8*)&Bs[((size_t)h * 128 + wn + j * 16 + fr) * 32 + fq * 8];
#pragma unroll
    for (int i = 0; i < 4; ++i)
#pragma unroll
      for (int j = 0; j < 4; ++j)
        acc[i][j] = __builtin_amdgcn_mfma_f32_16x16x32_bf16(a[i], b[j], acc[i][j], 0, 0, 0);
  }
  float mm[4][4], rr[4][4];
#pragma unroll
  for (int i = 0; i < 4; ++i)
#pragma unroll
    for (int r = 0; r < 4; ++r) {
      int m = m0 + wm + i * 16 + fq * 4 + r;
      mm[i][r] = mu1[m];
      rr[i][r] = rstd1[m];
    }
#pragma unroll
  for (int j = 0; j < 4; ++j) {
    const int n = n0 + wn + j * 16 + fr;
    const float ga = gamma[n], be = beta[n], dd = Dv[n];
#pragma unroll
    for (int i = 0; i < 4; ++i) {
      float xv[4];
#pragma unroll
      for (int r = 0; r < 4; ++r)
        xv[r] = x[(size_t)(m0 + wm + i * 16 + fq * 4 + r) * DMODEL + n];
#pragma unroll
      for (int r = 0; r < 4; ++r) {
        float yv = acc[i][j][r] + ((xv[r] - mm[i][r]) * rr[i][r] * ga + be) * dd + xv[r];
        out[(size_t)(m0 + wm + i * 16 + fq * 4 + r) * DMODEL + n] = yv;
      }
    }
  }
}

// ---------- K5: yn = bf16(LayerNorm(y)) ----------
__global__ void ln_apply_kernel(const float* __restrict__ y, const float* __restrict__ gamma,
                                const float* __restrict__ beta,
                                unsigned short* __restrict__ yn) {
  int row = blockIdx.x * 4 + (threadIdx.x >> 6);
  int lane = threadIdx.x & 63;
  const float4* yp = (const float4*)(y + (size_t)row * DMODEL);
  float4 a = yp[lane * 2];
  float4 b = yp[lane * 2 + 1];
  float s = a.x + a.y + a.z + a.w + b.x + b.y + b.z + b.w;
  float q = a.x * a.x + a.y * a.y + a.z * a.z + a.w * a.w + b.x * b.x + b.y * b.y +
            b.z * b.z + b.w * b.w;
  s = wave_sum(s);
  q = wave_sum(q);
  float m = s * (1.0f / DMODEL);
  float var = q * (1.0f / DMODEL) - m * m;
  float rs = rsqrtf(var + LN_EPS);
  const float4* gp = (const float4*)gamma;
  const float4* bp = (const float4*)beta;
  float4 g0 = gp[lane * 2], g1 = gp[lane * 2 + 1];
  float4 e0 = bp[lane * 2], e1 = bp[lane * 2 + 1];
  float o0x = (a.x - m) * rs * g0.x + e0.x, o0y = (a.y - m) * rs * g0.y + e0.y;
  float o0z = (a.z - m) * rs * g0.z + e0.z, o0w = (a.w - m) * rs * g0.w + e0.w;
  float o1x = (b.x - m) * rs * g1.x + e1.x, o1y = (b.y - m) * rs * g1.y + e1.y;
  float o1z = (b.z - m) * rs * g1.z + e1.z, o1w = (b.w - m) * rs * g1.w + e1.w;
  uint4 pk;
  pk.x = (unsigned)f2bf(o0x) | ((unsigned)f2bf(o0y) << 16);
  pk.y = (unsigned)f2bf(o0z) | ((unsigned)f2bf(o0w) << 16);
  pk.z = (unsigned)f2bf(o1x) | ((unsigned)f2bf(o1y) << 16);
  pk.w = (unsigned)f2bf(o1z) | ((unsigned)f2bf(o1w) << 16);
  ((uint4*)(yn + (size_t)row * DMODEL))[lane] = pk;
}

// ---------- MFMA MLP GEMM 1: g = bf16(gelu(yn @ W1 + b1)) ----------
__global__ __launch_bounds__(256) void mlp1_mfma_kernel(const unsigned short* __restrict__ yn,
                                                        const unsigned short* __restrict__ w1t,
                                                        const float* __restrict__ b1,
                                                        unsigned short* __restrict__ g) {
  __shared__ unsigned short As[128 * 32];
  __shared__ unsigned short Bs[128 * 32];
  const int t = threadIdx.x;
  const int wave = t >> 6, lane = t & 63;
  const int m0 = blockIdx.y * 128, n0 = blockIdx.x * 128;
  const int wm = (wave >> 1) * 64, wn = (wave & 1) * 64;
  const int row0 = t >> 2, seg0 = t & 3;
  const int row1 = (t + 256) >> 2;
  const unsigned short* gA0 = yn + (size_t)(m0 + row0) * 512 + seg0 * 8;
  const unsigned short* gA1 = yn + (size_t)(m0 + row1) * 512 + seg0 * 8;
  const unsigned short* gB0 = w1t + (size_t)(n0 + row0) * 512 + seg0 * 8;
  const unsigned short* gB1 = w1t + (size_t)(n0 + row1) * 512 + seg0 * 8;
  unsigned short* lA0 = As + (size_t)(wave * 64) * 8;
  unsigned short* lA1 = As + (size_t)(256 + wave * 64) * 8;
  unsigned short* lB0 = Bs + (size_t)(wave * 64) * 8;
  unsigned short* lB1 = Bs + (size_t)(256 + wave * 64) * 8;
  f32x4 acc[4][4] = {};
  const int fr = lane & 15, fq = lane >> 4;
  for (int k0 = 0; k0 < 512; k0 += 32) {
    __syncthreads();
    gl2lds16(gA0 + k0, lA0);
    gl2lds16(gA1 + k0, lA1);
    gl2lds16(gB0 + k0, lB0);
    gl2lds16(gB1 + k0, lB1);
    __syncthreads();
#pragma unroll
    for (int i = 0; i < 4; ++i) {
      bf16x8 a = *(const bf16x8*)&As[(wm + i * 16 + fr) * 32 + fq * 8];
#pragma unroll
      for (int j = 0; j < 4; ++j) {
        bf16x8 b = *(const bf16x8*)&Bs[(wn + j * 16 + fr) * 32 + fq * 8];
        acc[i][j] = __builtin_amdgcn_mfma_f32_16x16x32_bf16(a, b, acc[i][j], 0, 0, 0);
      }
    }
  }
#pragma unroll
  for (int i = 0; i < 4; ++i)
#pragma unroll
    for (int j = 0; j < 4; ++j) {
      const int cg = n0 + wn + j * 16 + fr;
      const float bb = b1[cg];
#pragma unroll
      for (int r = 0; r < 4; ++r) {
        const int rg = m0 + wm + i * 16 + fq * 4 + r;
        g[(size_t)rg * 1024 + cg] = f2bf(gelu_fast(acc[i][j][r] + bb));
      }
    }
}

// ---------- MFMA MLP GEMM 2: out = y + g @ W2 + b2 ----------
__global__ __launch_bounds__(256) void mlp2_mfma_kernel(const unsigned short* __restrict__ g,
                                                        const unsigned short* __restrict__ w2t,
                                                        const float* __restrict__ b2,
                                                        float* __restrict__ out) {
  __shared__ unsigned short As[128 * 32];
  __shared__ unsigned short Bs[128 * 32];
  const int t = threadIdx.x;
  const int wave = t >> 6, lane = t & 63;
  const int m0 = blockIdx.y * 128, n0 = blockIdx.x * 128;
  const int wm = (wave >> 1) * 64, wn = (wave & 1) * 64;
  const int row0 = t >> 2, seg0 = t & 3;
  const int row1 = (t + 256) >> 2;
  const unsigned short* gA0 = g + (size_t)(m0 + row0) * 1024 + seg0 * 8;
  const unsigned short* gA1 = g + (size_t)(m0 + row1) * 1024 + seg0 * 8;
  const unsigned short* gB0 = w2t + (size_t)(n0 + row0) * 1024 + seg0 * 8;
  const unsigned short* gB1 = w2t + (size_t)(n0 + row1) * 1024 + seg0 * 8;
  unsigned short* lA0 = As + (size_t)(wave * 64) * 8;
  unsigned short* lA1 = As + (size_t)(256 + wave * 64) * 8;
  unsigned short* lB0 = Bs + (size_t)(wave * 64) * 8;
  unsigned short* lB1 = Bs + (size_t)(256 + wave * 64) * 8;
  f32x4 acc[4][4] = {};
  const int fr = lane & 15, fq = lane >> 4;
  for (int k0 = 0; k0 < 1024; k0 += 32) {
    __syncthreads();
    gl2lds16(gA0 + k0, lA0);
    gl2lds16(gA1 + k0, lA1);
    gl2lds16(gB0 + k0, lB0);
    gl2lds16(gB1 + k0, lB1);
    __syncthreads();
#pragma unroll
    for (int i = 0; i < 4; ++i) {
      bf16x8 a = *(const bf16x8*)&As[(wm + i * 16 + fr) * 32 + fq * 8];
#pragma unroll
      for (int j = 0; j < 4; ++j) {
        bf16x8 b = *(const bf16x8*)&Bs[(wn + j * 16 + fr) * 32 + fq * 8];
        acc[i][j] = __builtin_amdgcn_mfma_f32_16x16x32_bf16(a, b, acc[i][j], 0, 0, 0);
      }
    }
  }
#pragma unroll
  for (int i = 0; i < 4; ++i)
#pragma unroll
    for (int j = 0; j < 4; ++j) {
      const int cg = n0 + wn + j * 16 + fr;
      const float bb = b2[cg];
#pragma unroll
      for (int r = 0; r < 4; ++r) {
        const int rg = m0 + wm + i * 16 + fq * 4 + r;
        const size_t off = (size_t)rg * 512 + cg;
        out[off] = out[off] + acc[i][j][r] + bb;
      }
    }
}

extern "C" void kernel_launch(void* const* d_in, const int* in_sizes, int n_in, void* d_out,
                              int out_size, void* d_ws, size_t ws_size, hipStream_t stream) {
  const float* x = (const float*)d_in[0];
  const float* logA = (const float*)d_in[1];
  const float* Bm = (const float*)d_in[2];
  const float* Cm = (const float*)d_in[3];
  const float* Dv = (const float*)d_in[4];
  const float* logdt = (const float*)d_in[5];
  const float* gamma = (const float*)d_in[6];
  const float* beta = (const float*)d_in[7];
  const float* W1 = (const float*)d_in[8];
  const float* b1 = (const float*)d_in[9];
  const float* W2 = (const float*)d_in[10];
  const float* b2 = (const float*)d_in[11];
  float* out = (float*)d_out;

  // workspace layout (bytes). xbf aliases the (later) g region.
  char* ws = (char*)d_ws;
  float* mu1 = (float*)(ws + 0);
  float* rstd1 = (float*)(ws + 131072);
  float* ends = (float*)(ws + 262144);
  float* gB = (float*)(ws + 524288);
  float* bB = (float*)(ws + 524800);
  unsigned short* Bgt = (unsigned short*)(ws + 525312);   // 64 KB [64][512]
  unsigned short* ctb = (unsigned short*)(ws + 590848);   // 64 KB [512][64]
  unsigned short* w1t = (unsigned short*)(ws + 656384);   // 1 MB  [1024][512]
  unsigned short* w2t = (unsigned short*)(ws + 1704960);  // 1 MB  [512][1024]
  unsigned short* g = (unsigned short*)(ws + 2753536);    // 64 MB [32768][1024]
  unsigned short* xbf = (unsigned short*)(ws + 2753536);  // 32 MB (dead before g written)
  float* xB = (float*)(ws + 69862400);                    // 8 MB [M][64]
  unsigned short* hsb = (unsigned short*)(ws + 78251008); // 4 MB bf16 [M][64]
  unsigned short* yn = (unsigned short*)(ws + 82445312);  // 32 MB bf16

  prep_all_kernel<<<280, 256, 0, stream>>>(W1, W2, Cm, Bm, gamma, beta, w1t, w2t, ctb, Bgt, gB,
                                           bB);
  ln_stats_kernel<<<MROWS / 4, 256, 0, stream>>>(x, mu1, rstd1, xbf);
  xb_mfma_kernel<<<MROWS / 128, 256, 0, stream>>>(xbf, Bgt, mu1, rstd1, gB, bB, xB);
  scan_ends_kernel<<<128, 256, 0, stream>>>(xB, logA, logdt, ends);
  scan_fix_kernel<<<128, 256, 0, stream>>>(logA, logdt, ends, xB, hsb);
  y_gemm_mfma_kernel<<<dim3(DMODEL / 128, MROWS / 128), 256, 0, stream>>>(
      hsb, ctb, x, mu1, rstd1, gamma, beta, Dv, out);
  ln_apply_kernel<<<MROWS / 4, 256, 0, stream>>>(out, gamma, beta, yn);
  mlp1_mfma_kernel<<<dim3(1024 / 128, MROWS / 128), 256, 0, stream>>>(yn, w1t, b1, g);
  mlp2_mfma_kernel<<<dim3(512 / 128, MROWS / 128), 256, 0, stream>>>(g, w2t, b2, out);
}